// Round 5
// baseline (375.137 us; speedup 1.0000x reference)
//
#include <hip/hip_runtime.h>
#include <math.h>

#define N    8192
#define BLK  256
#define NBLK 256            // 32 i's per block
#define TBLM 8191           // 8192-slot LDS hash table

// Single-dispatch NMS-hash kernel. Every block redundantly builds the full
// group table in LDS (64 KiB: tcode+tval), then ranks/scatters its own 32
// outputs. NO global atomics, NO fences, NO cross-block dependencies —
// R3/R4 showed grid-wide sync costs 80-240 µs (per-XCD L2 wb/inv storms)
// and each extra dispatch boundary costs ~6 µs.
//
// Verified math (absmax 0.0, R1-R4): i = rint((log512 - log w)/log 1.2)
// [f32 ops, (double) log/pow], di = 128/1.2^i, qx = rint(x/di - 0.5).
// Field bounds: qx,qy in [0,1035] (11 bits), i,j in [0,23] (5 bits).
// 5|5|11|11 pack is lexicographic in (j,i,qy,qx) == reference decimal
// code order. Max code <= 0xBBFFFFFF so tag=code+1 never wraps.
//
// Winner rule (== reference argmax over conf*assign): per group max conf,
// tie -> smallest index. Implemented as: P1 atomicMax(tval, conf_bits)
// [conf in [0,1) -> bits < 2^30]; P2 record conf==groupmax; P3 those
// threads atomicMax(tval, 0x40000000|(8191-j)) -> final tval encodes the
// min-index winner (0x4... > any conf bits, so it always supersedes).
// rank_i = #{claimed slots: code < ci} (each distinct code has exactly
// one winner); U = #claimed slots; out[>=U] zeroed (reference pads unique
// with fill -> all-zero score columns -> argmax 0). conf==0 winner -> its
// whole group is conf 0 -> reference argmax returns 0.
__global__ void __launch_bounds__(BLK)
k_nms(const float4* __restrict__ rects, const float* __restrict__ conf,
      int* __restrict__ out) {
    __shared__ unsigned int tcode[8192];   // 0 = empty, else code+1
    __shared__ unsigned int tval[8192];    // maxconf, then 0x40000000|(8191-jwin)

    const int t    = threadIdx.x;
    const int lane = t & 63;
    const float LOG_ALPHA = (float)log((double)1.2f);
    const float LOGW0     = (float)log(512.0);

    // Per-lane pow LUT: lane L holds (float)pow(1.2, L). i_f in [0,23];
    // (double)(float)lane == (double)i_f bit-exactly -> identical to the
    // verified per-element pow((double)1.2f,(double)i_f).
    float powL = (float)pow((double)1.2f, (double)(float)lane);

    // ---- P0: zero the table ----
    uint4* tc4 = (uint4*)tcode;
    uint4* tv4 = (uint4*)tval;
    #pragma unroll
    for (int k = 0; k < 8; ++k) {
        tc4[t + k * 256] = make_uint4(0u, 0u, 0u, 0u);
        tv4[t + k * 256] = make_uint4(0u, 0u, 0u, 0u);
    }
    __syncthreads();

    // ---- P1: codes + insert + conf-max (32 j's per thread, all in LDS) ----
    unsigned int hs[32];                 // slot of each of my j's (static idx)
    #pragma unroll
    for (int k = 0; k < 32; ++k) {
        int j = t + k * 256;
        float4 r = rects[j];
        float i_f = rintf((LOGW0 - (float)log((double)r.z)) / LOG_ALPHA);
        float j_f = rintf((LOGW0 - (float)log((double)r.w)) / LOG_ALPHA);
        float pi = __shfl(powL, (int)i_f);
        float pj = __shfl(powL, (int)j_f);
        float qx = rintf(r.x / (128.0f / pi) - 0.5f);
        float qy = rintf(r.y / (128.0f / pj) - 0.5f);
        unsigned int code = (unsigned int)qx | ((unsigned int)qy << 11)
                          | ((unsigned int)i_f << 22) | ((unsigned int)j_f << 27);
        unsigned int tag = code + 1u;
        unsigned int h = (code * 2654435761u) >> 19;   // 13-bit slot
        for (;;) {
            unsigned int prev = atomicCAS(&tcode[h], 0u, tag);
            if (prev == 0u || prev == tag) break;
            h = (h + 1) & TBLM;
        }
        hs[k] = h;
        atomicMax(&tval[h], __float_as_uint(conf[j]));
    }
    __syncthreads();

    // ---- P2: who matches the group max? (read before P3 overwrites) ----
    unsigned int eqmask = 0u;
    #pragma unroll
    for (int k = 0; k < 32; ++k) {
        int j = t + k * 256;
        eqmask |= (unsigned int)(__float_as_uint(conf[j]) == tval[hs[k]]) << k;
    }
    __syncthreads();

    // ---- P3: tie-break -> min index wins ----
    #pragma unroll
    for (int k = 0; k < 32; ++k) {
        if ((eqmask >> k) & 1u) {
            int j = t + k * 256;
            atomicMax(&tval[hs[k]], 0x40000000u | (unsigned int)(8191 - j));
        }
    }
    __syncthreads();

    // ---- P4: rank scan, 8 threads per i (32 i's per block) ----
    const int iloc = t >> 3, part = t & 7;
    const int i = blockIdx.x * 32 + iloc;
    float4 ri  = rects[i];
    float  cfi = conf[i];
    float i_f = rintf((LOGW0 - (float)log((double)ri.z)) / LOG_ALPHA);
    float j_f = rintf((LOGW0 - (float)log((double)ri.w)) / LOG_ALPHA);
    float pi = __shfl(powL, (int)i_f);
    float pj = __shfl(powL, (int)j_f);
    float qx = rintf(ri.x / (128.0f / pi) - 0.5f);
    float qy = rintf(ri.y / (128.0f / pj) - 0.5f);
    unsigned int ci = (unsigned int)qx | ((unsigned int)qy << 11)
                    | ((unsigned int)i_f << 22) | ((unsigned int)j_f << 27);
    unsigned int h = (ci * 2654435761u) >> 19;
    while (tcode[h] != ci + 1u) h = (h + 1) & TBLM;   // my slot (must exist)
    int win = (tval[h] == (0x40000000u | (unsigned int)(8191 - i)));

    // Each part scans 256 uint4s of tcode; rotation (kk+part)&255 makes the
    // 8 parts hit distinct bank-quads (q%8 = (kk+part)%8); across i-groups
    // same part -> same address -> broadcast. rank: tag-1 <u ci excludes
    // empty (0-1 wraps to max) and self (ci not < ci). u: claimed slots.
    int r = 0, u = 0;
    const uint4* tq = (const uint4*)tcode;
    #pragma unroll 8
    for (int kk = 0; kk < 256; ++kk) {
        uint4 c = tq[part * 256 + ((kk + part) & 255)];
        r += (int)(c.x - 1u < ci) + (int)(c.y - 1u < ci)
           + (int)(c.z - 1u < ci) + (int)(c.w - 1u < ci);
        u += (int)(c.x != 0u) + (int)(c.y != 0u)
           + (int)(c.z != 0u) + (int)(c.w != 0u);
    }
    // reduce r,u across the 8 parts (xor 1,2,4 stays inside the 8-lane group)
    r += __shfl_xor(r, 1); u += __shfl_xor(u, 1);
    r += __shfl_xor(r, 2); u += __shfl_xor(u, 2);
    r += __shfl_xor(r, 4); u += __shfl_xor(u, 4);

    if (part == 0 && win)
        out[r] = (cfi == 0.0f) ? 0 : i;     // winners: disjoint slots < U

    // ---- P5: block 0 zeroes the fill region [U, N) ----
    if (blockIdx.x == 0)
        for (int k2 = u + t; k2 < N; k2 += BLK) out[k2] = 0;
}

extern "C" void kernel_launch(void* const* d_in, const int* in_sizes, int n_in,
                              void* d_out, int out_size, void* d_ws, size_t ws_size,
                              hipStream_t stream) {
    const float4* rects = (const float4*)d_in[0];   // (8192, 4) f32
    const float*  conf  = (const float*)d_in[1];    // (8192,)  f32
    int* out = (int*)d_out;                         // int32 indices
    (void)d_ws; (void)ws_size;                      // workspace unused

    k_nms<<<NBLK, BLK, 0, stream>>>(rects, conf, out);
}

// Round 6
// 96.938 us; speedup vs baseline: 3.8699x; 3.8699x over previous
//
#include <hip/hip_runtime.h>
#include <math.h>

#define N    8192
#define TBL  16384            // hash slots = 2x N, load factor <= 0.5
#define TBLM 16383

// f32 hash pipeline — byte-identical math to the verified version (absmax
// 0.0 in R1-R5). Field bounds: qx,qy in [0,1035] (11 bits), i,j in [0,23]
// (5 bits). 5|5|11|11 pack is lexicographic in (j,i,qy,qx) — same
// order/equality as the reference decimal code. Max code <= 0xBBFFFFFF,
// so tag=code+1 never wraps and 0xFFFFFFFF never collides with a code.
__device__ __forceinline__ unsigned int hash_code32(float x, float y, float w, float h) {
    const float LOG_ALPHA = (float)log((double)1.2f);
    const float LOGW0     = (float)log(512.0);
    float i_f = rintf((LOGW0 - (float)log((double)w)) / LOG_ALPHA);
    float j_f = rintf((LOGW0 - (float)log((double)h)) / LOG_ALPHA);
    float pi  = (float)pow((double)1.2f, (double)i_f);
    float pj  = (float)pow((double)1.2f, (double)j_f);
    float qx  = rintf(x / (128.0f / pi) - 0.5f);
    float qy  = rintf(y / (128.0f / pj) - 0.5f);
    return (unsigned int)qx
         | ((unsigned int)qy  << 11)
         | ((unsigned int)i_f << 22)
         | ((unsigned int)j_f << 27);
}

__device__ __forceinline__ unsigned int hslot(unsigned int code) {
    return (code * 2654435761u) >> 18;   // top 14 bits -> [0, TBL)
}

// D1: zero table + compute codes + zero out. Plain stores only.
// 64 blocks x 256 = 16384 threads (R4-verified shape).
__global__ void __launch_bounds__(256)
k_init(const float4* __restrict__ rects, const float* __restrict__ conf,
       unsigned long long* __restrict__ v64,
       unsigned int* __restrict__ tcode, unsigned long long* __restrict__ tkey,
       int* __restrict__ out) {
    int gt = blockIdx.x * 256 + threadIdx.x;    // 0..16383
    tcode[gt] = 0u;            // empty = 0 (codes stored as code+1)
    tkey[gt]  = 0ULL;
    if (gt < N) {
        float4 r = rects[gt];
        unsigned int code = hash_code32(r.x, r.y, r.z, r.w);
        v64[gt] = ((unsigned long long)code << 32)
                | (unsigned long long)__float_as_uint(conf[gt]);
        out[gt] = 0;           // fill columns of reference argmax -> 0
    }
}

// D2: hash insert — EXACT R4-verified kernel. 32 blocks x 256. Claim slot
// by CAS, then group-argmax via 64-bit atomicMax of (conf_bits<<32|N-1-i):
// max conf, tie -> smaller index — exactly the reference argmax order.
__global__ void __launch_bounds__(256)
k_insert(const unsigned long long* __restrict__ v64,
         unsigned int* __restrict__ tcode,
         unsigned long long* __restrict__ tkey) {
    int i = blockIdx.x * 256 + threadIdx.x;
    unsigned long long v = v64[i];
    unsigned int code = (unsigned int)(v >> 32);
    unsigned int tag  = code + 1u;
    unsigned int h = hslot(code);
    for (;;) {
        unsigned int prev = atomicCAS(&tcode[h], 0u, tag);
        if (prev == 0u || prev == tag) break;
        h = (h + 1) & TBLM;
    }
    atomicMax(&tkey[h], (v << 32) | (unsigned int)(N - 1 - i));
}

// D3: rank + scatter, fully block-local (no cross-block communication —
// all inputs are post-D2 via the dispatch boundary). 256 blocks x 1024;
// block owns 32 i's. rank_i = #{claimed slots: slotcode < ci} (each
// distinct code claims exactly one slot, so this equals #distinct codes
// < ci — winner status NOT needed for rank). 32 lanes per i scan the
// LDS-staged table; shfl_xor-reduce; lane 0 does the O(1) winner lookup
// and scatters. Winners have globally distinct ranks in [0, U) — no
// write conflicts; out[U:] stays 0 from D1.
__global__ void __launch_bounds__(1024)
k_rank(const unsigned long long* __restrict__ v64,
       const unsigned int* __restrict__ tcode,
       const unsigned long long* __restrict__ tkey,
       int* __restrict__ out) {
    __shared__ unsigned int s_tc[TBL];          // 64 KiB table copy
    const int t = threadIdx.x;

    // stage table: 4096 uint4 loads, coalesced, linear LDS (conflict-free)
    uint4* s4 = (uint4*)s_tc;
    const uint4* g4 = (const uint4*)tcode;
    #pragma unroll
    for (int k = 0; k < 4; ++k) s4[t + k * 1024] = g4[t + k * 1024];
    __syncthreads();

    const int p  = t & 31;                      // scan part 0..31
    const int il = t >> 5;                      // local i 0..31
    const int i  = blockIdx.x * 32 + il;
    unsigned long long vi = v64[i];
    unsigned int ci = (unsigned int)(vi >> 32);

    // part p scans uint4 indices [128p, 128p+128); rotation (kk+p)&127
    // staggers bank-quads across parts. Lanes sharing p (two il's) read
    // the same address (broadcast pair). tag-1 <u ci excludes empty
    // (0-1 wraps to 0xFFFFFFFF >= any code) and self (ci not < ci).
    int r = 0;
    #pragma unroll 8
    for (int kk = 0; kk < 128; ++kk) {
        uint4 c = s4[p * 128 + ((kk + p) & 127)];
        r += (int)(c.x - 1u < ci) + (int)(c.y - 1u < ci)
           + (int)(c.z - 1u < ci) + (int)(c.w - 1u < ci);
    }
    // reduce across the 32 parts (xor 1..16 stays within the 32-lane group)
    r += __shfl_xor(r, 1);
    r += __shfl_xor(r, 2);
    r += __shfl_xor(r, 4);
    r += __shfl_xor(r, 8);
    r += __shfl_xor(r, 16);

    if (p == 0) {
        // winner check: probe LDS table for ci's slot, read global tkey.
        unsigned int tag = ci + 1u;
        unsigned int h = hslot(ci);
        while (s_tc[h] != tag) h = (h + 1) & TBLM;
        if ((unsigned int)tkey[h] == (unsigned int)(N - 1 - i)) {
            // conf==0 winner => whole group conf 0 => all-zero score
            // column => reference argmax returns 0.
            out[r] = ((unsigned int)vi == 0u) ? 0 : i;
        }
    }
}

extern "C" void kernel_launch(void* const* d_in, const int* in_sizes, int n_in,
                              void* d_out, int out_size, void* d_ws, size_t ws_size,
                              hipStream_t stream) {
    const float4* rects = (const float4*)d_in[0];   // (8192, 4) f32
    const float*  conf  = (const float*)d_in[1];    // (8192,)  f32
    int* out = (int*)d_out;                         // int32 indices

    char* ws = (char*)d_ws;
    unsigned long long* v64   = (unsigned long long*)ws;             // 64 KiB
    unsigned int*       tcode = (unsigned int*)(ws + 65536);         // 64 KiB
    unsigned long long* tkey  = (unsigned long long*)(ws + 131072);  // 128 KiB

    k_init  <<<TBL / 256, 256, 0, stream>>>(rects, conf, v64, tcode, tkey, out);
    k_insert<<<N / 256, 256, 0, stream>>>(v64, tcode, tkey);
    k_rank  <<<256, 1024, 0, stream>>>(v64, tcode, tkey, out);
}

// Round 7
// 73.164 us; speedup vs baseline: 5.1273x; 1.3249x over previous
//
#include <hip/hip_runtime.h>
#include <math.h>

#define N     8192
#define TBL   16384           // hash slots = 2x N
#define TBLM  16383

// f32 hash pipeline — byte-identical math to the verified version (absmax
// 0.0 in R1-R6). Field bounds: qx,qy in [0,1035] (11 bits), i,j in [0,23]
// (5 bits). 5|5|11|11 pack is lexicographic in (j,i,qy,qx) — same
// order/equality as the reference decimal code. Max code <= 0xBDE05C0B,
// so tag=code+1 never wraps and 0xFFFFFFFF is a safe pad sentinel.
__device__ __forceinline__ unsigned int hash_code32(float x, float y, float w, float h) {
    const float LOG_ALPHA = (float)log((double)1.2f);
    const float LOGW0     = (float)log(512.0);
    float i_f = rintf((LOGW0 - (float)log((double)w)) / LOG_ALPHA);
    float j_f = rintf((LOGW0 - (float)log((double)h)) / LOG_ALPHA);
    float pi  = (float)pow((double)1.2f, (double)i_f);
    float pj  = (float)pow((double)1.2f, (double)j_f);
    float qx  = rintf(x / (128.0f / pi) - 0.5f);
    float qy  = rintf(y / (128.0f / pj) - 0.5f);
    return (unsigned int)qx
         | ((unsigned int)qy  << 11)
         | ((unsigned int)i_f << 22)
         | ((unsigned int)j_f << 27);
}

__device__ __forceinline__ unsigned int hslot(unsigned int code) {
    return (code * 2654435761u) >> 18;   // top 14 bits -> [0, TBL)
}

// D1: zero table/cnt + codes + pad compact + zero out. Plain stores only.
__global__ void __launch_bounds__(256)
k_init(const float4* __restrict__ rects, const float* __restrict__ conf,
       unsigned long long* __restrict__ v64,
       unsigned int* __restrict__ tcode, unsigned long long* __restrict__ tkey,
       unsigned int* __restrict__ compact, unsigned int* __restrict__ cnt,
       int* __restrict__ out) {
    int gt = blockIdx.x * 256 + threadIdx.x;    // 0..16383
    tcode[gt] = 0u;            // empty = 0 (codes stored as code+1)
    tkey[gt]  = 0ULL;
    if (gt < N) {
        float4 r = rects[gt];
        unsigned int code = hash_code32(r.x, r.y, r.z, r.w);
        v64[gt] = ((unsigned long long)code << 32)
                | (unsigned long long)__float_as_uint(conf[gt]);
        out[gt]     = 0;            // fill columns of reference argmax -> 0
        compact[gt] = 0xFFFFFFFFu;  // pad: > any real code, never counted
    }
    if (gt == 0) *cnt = 0u;
}

// D2: hash insert (R4-verified CAS + 64-bit atomicMax argmax order) + NEW:
// slot claimers append their distinct code to the dense compact[] array
// via ONE wave-aggregated atomicAdd per wave. 128 blocks x 64 (1 wave).
__global__ void __launch_bounds__(64)
k_insert(const unsigned long long* __restrict__ v64,
         unsigned int* __restrict__ tcode,
         unsigned long long* __restrict__ tkey,
         unsigned int* __restrict__ compact,
         unsigned int* __restrict__ cnt) {
    int i = blockIdx.x * 64 + threadIdx.x;
    int lane = threadIdx.x;
    unsigned long long v = v64[i];
    unsigned int code = (unsigned int)(v >> 32);
    unsigned int tag  = code + 1u;
    unsigned int h = hslot(code);
    bool claimed = false;
    for (;;) {
        unsigned int prev = atomicCAS(&tcode[h], 0u, tag);
        if (prev == 0u) { claimed = true; break; }
        if (prev == tag) break;
        h = (h + 1) & TBLM;
    }
    // key: max conf, tie -> smaller index (reference argmax order)
    atomicMax(&tkey[h], (v << 32) | (unsigned int)(N - 1 - i));
    // exactly one claimer per distinct code -> dense append
    unsigned long long mask = __ballot(claimed);
    if (mask) {
        int leader = __ffsll((long long)mask) - 1;
        unsigned int base = 0;
        if (lane == leader)
            base = atomicAdd(cnt, (unsigned int)__popcll(mask));
        base = (unsigned int)__shfl((int)base, leader);
        if (claimed) {
            unsigned int off = (unsigned int)__popcll(
                mask & ((1ULL << lane) - 1ULL));
            compact[base + off] = code;
        }
    }
}

// D3: register-tiled rank + scatter. 256 blocks x 512; block owns 32 i's.
// NO LDS table scan (R6's k_rank was DS-issue-bound with inherent 4-way
// b128 conflicts): each thread streams a disjoint chunk of compact[]
// straight from global (coalesced, each uint4 read once per group) and
// compares 4 codes x 8 i's per load — pure VALU (v_cmp+v_addc), i-codes
// hoisted to SGPRs via readfirstlane. rank_i = #{distinct codes < ci}
// (pad 0xFFFFFFFF never counts; self ci not < ci).
__global__ void __launch_bounds__(512)
k_rank(const unsigned long long* __restrict__ v64,
       const unsigned int* __restrict__ tcode,
       const unsigned long long* __restrict__ tkey,
       const unsigned int* __restrict__ compact,
       int* __restrict__ out) {
    __shared__ unsigned int s_ci[32];
    __shared__ int s_part[8][32];        // [wave][i_local]
    const int t = threadIdx.x;
    const int b = blockIdx.x;
    if (t < 32) s_ci[t] = (unsigned int)(v64[b * 32 + t] >> 32);
    __syncthreads();

    const int g    = t >> 7;             // 4 groups x 128 threads (2 waves)
    const int lt   = t & 127;
    const int wave = t >> 6;             // 0..7 (wave's group = wave>>1)

    // group g ranks i-locals [g*8, g*8+8); wave-uniform -> SGPR
    unsigned int ci[8];
    #pragma unroll
    for (int q = 0; q < 8; ++q)
        ci[q] = __builtin_amdgcn_readfirstlane(s_ci[g * 8 + q]);

    int r[8] = {0, 0, 0, 0, 0, 0, 0, 0};
    const uint4* c4 = (const uint4*)compact;   // 2048 uint4 = 8192 entries
    #pragma unroll
    for (int k = 0; k < 16; ++k) {
        uint4 e = c4[lt + k * 128];
        #pragma unroll
        for (int q = 0; q < 8; ++q) {
            r[q] += (int)(e.x < ci[q]) + (int)(e.y < ci[q])
                  + (int)(e.z < ci[q]) + (int)(e.w < ci[q]);
        }
    }
    // reduce each r[q] across the wave's 64 lanes
    #pragma unroll
    for (int q = 0; q < 8; ++q) {
        r[q] += __shfl_xor(r[q], 1);
        r[q] += __shfl_xor(r[q], 2);
        r[q] += __shfl_xor(r[q], 4);
        r[q] += __shfl_xor(r[q], 8);
        r[q] += __shfl_xor(r[q], 16);
        r[q] += __shfl_xor(r[q], 32);
    }
    if ((t & 63) == 0) {
        #pragma unroll
        for (int q = 0; q < 8; ++q)
            s_part[wave][(wave >> 1) * 8 + q] = r[q];
    }
    __syncthreads();

    if (t < 32) {
        int i = b * 32 + t;
        int gg = t >> 3;                 // group owning this i_local
        int rr = s_part[2 * gg][t] + s_part[2 * gg + 1][t];
        unsigned long long vi = v64[i];
        unsigned int cI = (unsigned int)(vi >> 32);
        unsigned int h = hslot(cI);
        while (tcode[h] != cI + 1u) h = (h + 1) & TBLM;
        if ((unsigned int)tkey[h] == (unsigned int)(N - 1 - i)) {
            // conf==0 winner => whole group conf 0 => all-zero score
            // column => reference argmax returns 0.
            out[rr] = ((unsigned int)vi == 0u) ? 0 : i;
        }
    }
}

extern "C" void kernel_launch(void* const* d_in, const int* in_sizes, int n_in,
                              void* d_out, int out_size, void* d_ws, size_t ws_size,
                              hipStream_t stream) {
    const float4* rects = (const float4*)d_in[0];   // (8192, 4) f32
    const float*  conf  = (const float*)d_in[1];    // (8192,)  f32
    int* out = (int*)d_out;                         // int32 indices

    char* ws = (char*)d_ws;
    unsigned long long* v64     = (unsigned long long*)ws;             // 64 KiB
    unsigned int*       tcode   = (unsigned int*)(ws + 65536);         // 64 KiB
    unsigned long long* tkey    = (unsigned long long*)(ws + 131072);  // 128 KiB
    unsigned int*       compact = (unsigned int*)(ws + 262144);        // 32 KiB
    unsigned int*       cnt     = (unsigned int*)(ws + 294912);        // 4 B

    k_init  <<<TBL / 256, 256, 0, stream>>>(rects, conf, v64, tcode, tkey,
                                            compact, cnt, out);
    k_insert<<<N / 64, 64, 0, stream>>>(v64, tcode, tkey, compact, cnt);
    k_rank  <<<256, 512, 0, stream>>>(v64, tcode, tkey, compact, out);
}